// Round 7
// baseline (60.208 us; speedup 1.0000x reference)
//
#include <hip/hip_runtime.h>
#include <hip/hip_bf16.h>

#define B_ 4
#define T_ 4096
#define C_ 1024
#define H_ 64

typedef float  f32x4  __attribute__((ext_vector_type(4)));
typedef short  bf16x8 __attribute__((ext_vector_type(8)));
typedef uint   u32x4  __attribute__((ext_vector_type(4)));

static __device__ __forceinline__ ushort f2bf(float f) {
  union { float f; uint u; } v; v.f = f;
  uint u = v.u;
  u += 0x7FFFu + ((u >> 16) & 1u);   // round-to-nearest-even
  return (ushort)(u >> 16);
}

// pack two f32 -> u32 of 2 bf16 (lo = s0, hi = s1), RTNE  [gfx950; no builtin]
static __device__ __forceinline__ uint cvtpk(float s0, float s1) {
  uint r;
  asm("v_cvt_pk_bf16_f32 %0, %1, %2" : "=v"(r) : "v"(s0), "v"(s1));
  return r;
}

static __device__ __forceinline__ void gload_lds16(const void* g, void* l) {
  __builtin_amdgcn_global_load_lds(
      (const __attribute__((address_space(1))) unsigned int*)g,
      (__attribute__((address_space(3))) unsigned int*)l, 16, 0, 0);
}

#define MFMA(a, b, c) __builtin_amdgcn_mfma_f32_16x16x32_bf16(a, b, c, 0, 0, 0)

// ---------------------------------------------------------------------------
// WtF: W in B-frag order: [w][c64 16][kc 2][nt 4][lane 64][j 8]
//   value = W_w[c = c64*64 + kc*32 + (lane>>4)*8 + j][n = nt*16 + (lane&15)]
__global__ __launch_bounds__(256) void wt_prep(const float* __restrict__ Wq,
                                               const float* __restrict__ Wk,
                                               const float* __restrict__ Wv,
                                               ushort* __restrict__ WtF) {
  int idx = blockIdx.x * 256 + threadIdx.x;   // 3*16*2*4*64*8 = 196608
  int j = idx & 7, lane = (idx >> 3) & 63, nt = (idx >> 9) & 3;
  int kc = (idx >> 11) & 1, c64 = (idx >> 12) & 15, w = idx >> 16;
  int l15 = lane & 15, g = lane >> 4;
  int c = c64 * 64 + kc * 32 + g * 8 + j;
  int n = nt * 16 + l15;
  const float* W = (w == 0) ? Wq : (w == 1) ? Wk : Wv;
  WtF[idx] = f2bf(W[c * 64 + n]);
}

// ---------------------------------------------------------------------------
// QKV projection v4 (unchanged from R6): 4-wave blocks, x direct-to-A-frag
// 2-deep prefetch, W via global_load_lds dbuf, counted-vmcnt raw barriers.
__global__ __launch_bounds__(256) void qkv_proj(const float* __restrict__ x,
                                                const ushort* __restrict__ WtF,
                                                ushort* __restrict__ Qg,
                                                char* __restrict__ KaF,
                                                char* __restrict__ VaF) {
  __shared__ __align__(16) ushort wl[2][12288];   // 2 x 24KB W frags
  const int tid = threadIdx.x;
  const int lane = tid & 63, wid = tid >> 6;
  const int l15 = lane & 15, g = lane >> 4;
  const int b = blockIdx.x >> 6, rt = blockIdx.x & 63;
  const int wrow = rt * 64 + wid * 16;            // wave's 16 rows

  f32x4 acc[3][4];
  #pragma unroll
  for (int w = 0; w < 3; w++)
    #pragma unroll
    for (int nt = 0; nt < 4; nt++) acc[w][nt] = (f32x4)0.0f;

  const float* xr = x + ((size_t)b * T_ + wrow + l15) * C_ + g * 8;

  auto stagew = [&](int buf, int c64) {
    char* dst = (char*)wl[buf] + tid * 16;
    const char* src = (const char*)WtF + (size_t)c64 * 8192 + tid * 16;
    #pragma unroll
    for (int p = 0; p < 6; p++)   // p = w*2 + half(4KB)
      gload_lds16(src + (p >> 1) * 131072 + (p & 1) * 4096, dst + p * 4096);
  };

  f32x4 xp[3][4];                 // 2-deep x prefetch ring (fully unrolled)
  auto xload = [&](int slot, int t) {
    const float* src = xr + t * 64;
    xp[slot][0] = *(const f32x4*)src;
    xp[slot][1] = *(const f32x4*)(src + 4);
    xp[slot][2] = *(const f32x4*)(src + 32);
    xp[slot][3] = *(const f32x4*)(src + 36);
  };

  stagew(0, 0);
  xload(0, 0);
  xload(1, 1);
  asm volatile("s_waitcnt vmcnt(8)" ::: "memory");   // stagew(0) landed
  __builtin_amdgcn_s_barrier();
  __builtin_amdgcn_sched_barrier(0);

  #pragma unroll
  for (int t = 0; t < 16; t++) {
    const int cur = t & 1;
    if (t < 15) stagew(cur ^ 1, t + 1);
    if (t < 14) xload((t + 2) % 3, t + 2);

    const int slot = t % 3;
    bf16x8 xa[2];
    #pragma unroll
    for (int kc = 0; kc < 2; kc++) {
      union { uint u[4]; bf16x8 v; } h;
      f32x4 c0 = xp[slot][2 * kc], c1 = xp[slot][2 * kc + 1];
      h.u[0] = cvtpk(c0[0], c0[1]); h.u[1] = cvtpk(c0[2], c0[3]);
      h.u[2] = cvtpk(c1[0], c1[1]); h.u[3] = cvtpk(c1[2], c1[3]);
      xa[kc] = h.v;
    }
    const char* wb = (const char*)wl[cur] + lane * 16;
    __builtin_amdgcn_s_setprio(1);
    #pragma unroll
    for (int w = 0; w < 3; w++)
      #pragma unroll
      for (int kc = 0; kc < 2; kc++)
        #pragma unroll
        for (int nt = 0; nt < 4; nt++) {
          bf16x8 wf = *(const bf16x8*)(wb + w * 8192 + kc * 4096 + nt * 1024);
          acc[w][nt] = MFMA(xa[kc], wf, acc[w][nt]);
        }
    __builtin_amdgcn_s_setprio(0);

    if (t < 15) {
      if (t < 14) asm volatile("s_waitcnt vmcnt(4)" ::: "memory");
      else        asm volatile("s_waitcnt vmcnt(0)" ::: "memory");
      __builtin_amdgcn_s_barrier();
      __builtin_amdgcn_sched_barrier(0);
    }
  }

  // epilogue: C-frag col = l15 (n), row = g*4 + r (t offset)  [m89-verified]
  char* kdst = KaF + ((size_t)b * 64 + rt) * 8192;
  char* vdst = VaF + ((size_t)b * 128 + (wrow >> 5)) * 4096;
  #pragma unroll
  for (int nt = 0; nt < 4; nt++) {
    int n = nt * 16 + l15;
    int kc = n >> 5, gp2 = (n >> 3) & 3, j2 = n & 7;
    #pragma unroll
    for (int r = 0; r < 4; r++) {
      int tt = wrow + g * 4 + r;
      Qg[((size_t)b * T_ + tt) * H_ + n] = f2bf(acc[0][nt][r]);
      int key = tt & 63;
      *(ushort*)(kdst + kc * 4096 + (key >> 4) * 1024 +
                 (gp2 * 16 + (key & 15)) * 16 + j2 * 2) = f2bf(acc[1][nt][r]);
      int k5 = tt & 31;
      int gp = ((k5 >> 4) << 1) | ((k5 >> 2) & 1);
      int js = ((k5 >> 3) & 1) * 4 + (k5 & 3);
      *(ushort*)(vdst + nt * 1024 + (gp * 16 + l15) * 16 + js * 2) = f2bf(acc[2][nt][r]);
    }
  }
}

// ---------------------------------------------------------------------------
// Flash attention v5: 64 q-rows/wave (4 subtiles), 256 q/block. K/V tile
// (16KB, frag-ordered) staged to block-shared LDS via global_load_lds,
// double-buffered, one vmcnt(0)+barrier per 64-key iter. Each frag read
// from LDS feeds 4 MFMAs -> LDS traffic halved vs S=2, L2 traffic 8x down.
__global__ __launch_bounds__(256, 2) void attn(const ushort* __restrict__ Qg,
                                               const char* __restrict__ KaF,
                                               const char* __restrict__ VaF,
                                               float* __restrict__ Op,
                                               float* __restrict__ Ds,
                                               float* __restrict__ out,
                                               int KT) {
  __shared__ __align__(16) char kv[2][16384];   // [buf][K 8KB | V 8KB]
  const int tid = threadIdx.x;
  const int lane = tid & 63, wid = tid >> 6;
  const int bid = blockIdx.x;
  const int b = bid & 3;                 // XCD spread over batches
  const int qt = (bid >> 2) & 15, s = bid >> 6;
  const int l15 = lane & 15, g = lane >> 4;

  // Q B-frags for 4 q-subtiles: lane l15 = q, k = dim g*8+j
  bf16x8 qa[4][2];
  #pragma unroll
  for (int qs = 0; qs < 4; qs++) {
    const ushort* qp = Qg + ((size_t)b * T_ + qt * 256 + wid * 64 + qs * 16 + l15) * H_ + g * 8;
    qa[qs][0] = *(const bf16x8*)qp;
    qa[qs][1] = *(const bf16x8*)(qp + 32);
  }

  f32x4 oacc[4][4];       // C: O[q=l15][dim = 16*ntd + g*4 + r] per subtile
  #pragma unroll
  for (int qs = 0; qs < 4; qs++)
    #pragma unroll
    for (int nt = 0; nt < 4; nt++) oacc[qs][nt] = (f32x4)0.0f;
  float dsum[4] = {0.f, 0.f, 0.f, 0.f};

  const char* kbase = KaF + (size_t)b * 64 * 8192;
  const char* vbase = VaF + (size_t)b * 128 * 4096;
  const int it0 = s * KT;

  auto stage = [&](int buf, int it) {
    char* dst = kv[buf] + tid * 16;
    const char* ks = kbase + (size_t)it * 8192 + tid * 16;
    const char* vs = vbase + (size_t)it * 8192 + tid * 16;
    gload_lds16(ks, dst);
    gload_lds16(ks + 4096, dst + 4096);
    gload_lds16(vs, dst + 8192);
    gload_lds16(vs + 4096, dst + 12288);
  };

  stage(0, it0);
  asm volatile("s_waitcnt vmcnt(0)" ::: "memory");
  __builtin_amdgcn_s_barrier();
  __builtin_amdgcn_sched_barrier(0);

  for (int it = 0; it < KT; it++) {
    const int cur = it & 1;
    if (it + 1 < KT) stage(cur ^ 1, it0 + it + 1);
    const char* kl = kv[cur];
    const char* vl = kv[cur] + 8192;

    // S^T = K Q^T: each K frag read once, feeds 4 subtiles
    f32x4 sacc[4][4];
    #pragma unroll
    for (int qs = 0; qs < 4; qs++)
      #pragma unroll
      for (int nt = 0; nt < 4; nt++) sacc[qs][nt] = (f32x4)0.0f;
    __builtin_amdgcn_s_setprio(1);
    #pragma unroll
    for (int nt = 0; nt < 4; nt++)
      #pragma unroll
      for (int kc = 0; kc < 2; kc++) {
        bf16x8 ka = *(const bf16x8*)(kl + kc * 4096 + nt * 1024 + lane * 16);
        #pragma unroll
        for (int qs = 0; qs < 4; qs++)
          sacc[qs][nt] = MFMA(ka, qa[qs][kc], sacc[qs][nt]);
      }
    __builtin_amdgcn_s_setprio(0);

    // softmax numerators in-register
    uint t0[4][4], t1[4][4];
    #pragma unroll
    for (int qs = 0; qs < 4; qs++)
      #pragma unroll
      for (int nt = 0; nt < 4; nt++) {
        float p0 = __builtin_amdgcn_exp2f(sacc[qs][nt][0] * 0.18033688011112042f);
        float p1 = __builtin_amdgcn_exp2f(sacc[qs][nt][1] * 0.18033688011112042f);
        float p2 = __builtin_amdgcn_exp2f(sacc[qs][nt][2] * 0.18033688011112042f);
        float p3 = __builtin_amdgcn_exp2f(sacc[qs][nt][3] * 0.18033688011112042f);
        dsum[qs] += (p0 + p1) + (p2 + p3);
        t0[qs][nt] = cvtpk(p0, p1);
        t1[qs][nt] = cvtpk(p2, p3);
      }

    // build P^T B-frags (permlane32_swap) and accumulate O^T += V^T P^T
    #pragma unroll
    for (int kk = 0; kk < 2; kk++) {
      bf16x8 pf[4];
      #pragma unroll
      for (int qs = 0; qs < 4; qs++) {
        uint x0 = t0[qs][2 * kk], y0 = t0[qs][2 * kk + 1];
        uint x1 = t1[qs][2 * kk], y1 = t1[qs][2 * kk + 1];
        asm volatile("v_permlane32_swap_b32 %0, %1" : "+v"(x0), "+v"(y0));
        asm volatile("v_permlane32_swap_b32 %0, %1" : "+v"(x1), "+v"(y1));
        union { uint u[4]; bf16x8 v; } pfu;
        pfu.u[0] = x0; pfu.u[1] = x1; pfu.u[2] = y0; pfu.u[3] = y1;
        pf[qs] = pfu.v;
      }
      __builtin_amdgcn_s_setprio(1);
      #pragma unroll
      for (int ntd = 0; ntd < 4; ntd++) {
        bf16x8 va = *(const bf16x8*)(vl + kk * 4096 + ntd * 1024 + lane * 16);
        #pragma unroll
        for (int qs = 0; qs < 4; qs++)
          oacc[qs][ntd] = MFMA(va, pf[qs], oacc[qs][ntd]);
      }
      __builtin_amdgcn_s_setprio(0);
    }

    if (it + 1 < KT) {
      asm volatile("s_waitcnt vmcnt(0)" ::: "memory");   // stage(it+1) is ~1 iter old
      __builtin_amdgcn_s_barrier();
      __builtin_amdgcn_sched_barrier(0);
    }
  }

  // epilogue per subtile
  #pragma unroll
  for (int qs = 0; qs < 4; qs++) {
    float d = dsum[qs];
    d += __shfl_xor(d, 16, 64);
    d += __shfl_xor(d, 32, 64);
    const int q = qt * 256 + wid * 64 + qs * 16 + l15;
    if (Op != nullptr) {
      float* ob = Op + ((size_t)(s * 4 + b) * T_ + q) * H_;
      #pragma unroll
      for (int nt = 0; nt < 4; nt++)
        #pragma unroll
        for (int r = 0; r < 4; r++) ob[nt * 16 + g * 4 + r] = oacc[qs][nt][r];
      if (g == 0) Ds[(size_t)(s * 4 + b) * T_ + q] = d;
    } else {
      float inv = 1.0f / d;
      float* ob = out + ((size_t)b * T_ + q) * H_;
      #pragma unroll
      for (int nt = 0; nt < 4; nt++)
        #pragma unroll
        for (int r = 0; r < 4; r++) ob[nt * 16 + g * 4 + r] = oacc[qs][nt][r] * inv;
    }
  }
}

// ---------------------------------------------------------------------------
// out[row][h] = sum_s Op[s][row][h] / sum_s Ds[s][row]
__global__ __launch_bounds__(256) void reduce_seg(const float* __restrict__ Op,
                                                  const float* __restrict__ Ds,
                                                  float* __restrict__ out, int seg) {
  int i = blockIdx.x * 256 + threadIdx.x;       // over 4*4096*16 f32x4 groups
  size_t e = (size_t)i * 4;
  int row = (int)(e >> 6);
  f32x4 o = (f32x4)0.0f;
  float d = 0.0f;
  for (int s = 0; s < seg; s++) {
    o += *(const f32x4*)(Op + (size_t)s * (4u * T_ * H_) + e);
    d += Ds[(size_t)s * (4u * T_) + row];
  }
  *(f32x4*)(out + e) = o * (1.0f / d);
}

// ---------------------------------------------------------------------------
extern "C" void kernel_launch(void* const* d_in, const int* in_sizes, int n_in,
                              void* d_out, int out_size, void* d_ws, size_t ws_size,
                              hipStream_t stream) {
  const float* x  = (const float*)d_in[0];
  const float* Wq = (const float*)d_in[1];
  const float* Wk = (const float*)d_in[2];
  const float* Wv = (const float*)d_in[3];
  float* out = (float*)d_out;

  char* ws = (char*)d_ws;
  size_t off = 0;
  auto take = [&](size_t n) -> void* {
    void* p = ws + off;
    off = (off + n + 255) & ~(size_t)255;
    return p;
  };
  ushort* Qg  = (ushort*)take((size_t)B_ * T_ * H_ * 2);   // 2 MB
  char*   KaF = (char*)take((size_t)B_ * T_ * H_ * 2);     // 2 MB (frag order)
  char*   VaF = (char*)take((size_t)B_ * T_ * H_ * 2);     // 2 MB (frag order)
  ushort* WtF = (ushort*)take((size_t)3 * H_ * C_ * 2);    // 384 KB

  // key-split: largest seg whose partials fit the workspace
  int seg = 1;
  float* Op = nullptr;
  float* Ds = nullptr;
  for (int sg = 8; sg >= 2; sg >>= 1) {
    size_t need = off + (size_t)sg * B_ * T_ * H_ * 4 + 256 + (size_t)sg * B_ * T_ * 4 + 256;
    if (need <= ws_size) {
      seg = sg;
      Op = (float*)take((size_t)sg * B_ * T_ * H_ * 4);
      Ds = (float*)take((size_t)sg * B_ * T_ * 4);
      break;
    }
  }
  int KT = 64 / seg;                                       // 64-key tiles/segment

  wt_prep<<<768, 256, 0, stream>>>(Wq, Wk, Wv, WtF);
  qkv_proj<<<B_ * 64, 256, 0, stream>>>(x, WtF, Qg, KaF, VaF);
  attn<<<B_ * (T_ / 256) * seg, 256, 0, stream>>>(Qg, KaF, VaF, Op, Ds, out, KT);
  if (Op) reduce_seg<<<(B_ * T_ * H_ / 4 + 255) / 256, 256, 0, stream>>>(Op, Ds, out, seg);
}

// Round 8
// 55.601 us; speedup vs baseline: 1.0829x; 1.0829x over previous
//
#include <hip/hip_runtime.h>
#include <hip/hip_bf16.h>

#define B_ 4
#define T_ 4096
#define C_ 1024
#define H_ 64

typedef float  f32x4  __attribute__((ext_vector_type(4)));
typedef short  bf16x8 __attribute__((ext_vector_type(8)));
typedef uint   u32x4  __attribute__((ext_vector_type(4)));

static __device__ __forceinline__ ushort f2bf(float f) {
  union { float f; uint u; } v; v.f = f;
  uint u = v.u;
  u += 0x7FFFu + ((u >> 16) & 1u);   // round-to-nearest-even
  return (ushort)(u >> 16);
}

// pack two f32 -> u32 of 2 bf16 (lo = s0, hi = s1), RTNE  [gfx950; no builtin]
static __device__ __forceinline__ uint cvtpk(float s0, float s1) {
  uint r;
  asm("v_cvt_pk_bf16_f32 %0, %1, %2" : "=v"(r) : "v"(s0), "v"(s1));
  return r;
}

static __device__ __forceinline__ void gload_lds16(const void* g, void* l) {
  __builtin_amdgcn_global_load_lds(
      (const __attribute__((address_space(1))) unsigned int*)g,
      (__attribute__((address_space(3))) unsigned int*)l, 16, 0, 0);
}

#define MFMA(a, b, c) __builtin_amdgcn_mfma_f32_16x16x32_bf16(a, b, c, 0, 0, 0)

// ---------------------------------------------------------------------------
// WtF: W in B-frag order: [w][c64 16][kc 2][nt 4][lane 64][j 8]
//   value = W_w[c][n], c = c64*64+kc*32+(lane>>4)*8+j, n = nt*16+(lane&15)
// Coalesced read version: thread reads W[idx2] linearly, scatters to WtF.
__global__ __launch_bounds__(256) void wt_prep(const float* __restrict__ Wq,
                                               const float* __restrict__ Wk,
                                               const float* __restrict__ Wv,
                                               ushort* __restrict__ WtF) {
  int idx = blockIdx.x * 256 + threadIdx.x;   // 3*65536
  int w = idx >> 16, idx2 = idx & 65535;
  int c = idx2 >> 6, n = idx2 & 63;
  const float* W = (w == 0) ? Wq : (w == 1) ? Wk : Wv;
  float v = W[idx2];
  int c64 = c >> 6, kc = (c >> 5) & 1, g = (c >> 3) & 3, j = c & 7;
  int nt = n >> 4, l15 = n & 15;
  size_t dst = ((size_t)((((w * 16 + c64) * 2 + kc) * 4 + nt) * 64 + g * 16 + l15)) * 8 + j;
  WtF[dst] = f2bf(v);
}

// ---------------------------------------------------------------------------
// QKV projection v4 (unchanged from R6): 4-wave blocks, x direct-to-A-frag
// 2-deep prefetch, W via global_load_lds dbuf, counted-vmcnt raw barriers.
__global__ __launch_bounds__(256) void qkv_proj(const float* __restrict__ x,
                                                const ushort* __restrict__ WtF,
                                                ushort* __restrict__ Qg,
                                                char* __restrict__ KaF,
                                                char* __restrict__ VaF) {
  __shared__ __align__(16) ushort wl[2][12288];   // 2 x 24KB W frags
  const int tid = threadIdx.x;
  const int lane = tid & 63, wid = tid >> 6;
  const int l15 = lane & 15, g = lane >> 4;
  const int b = blockIdx.x >> 6, rt = blockIdx.x & 63;
  const int wrow = rt * 64 + wid * 16;            // wave's 16 rows

  f32x4 acc[3][4];
  #pragma unroll
  for (int w = 0; w < 3; w++)
    #pragma unroll
    for (int nt = 0; nt < 4; nt++) acc[w][nt] = (f32x4)0.0f;

  const float* xr = x + ((size_t)b * T_ + wrow + l15) * C_ + g * 8;

  auto stagew = [&](int buf, int c64) {
    char* dst = (char*)wl[buf] + tid * 16;
    const char* src = (const char*)WtF + (size_t)c64 * 8192 + tid * 16;
    #pragma unroll
    for (int p = 0; p < 6; p++)   // p = w*2 + half(4KB)
      gload_lds16(src + (p >> 1) * 131072 + (p & 1) * 4096, dst + p * 4096);
  };

  f32x4 xp[3][4];                 // 2-deep x prefetch ring (fully unrolled)
  auto xload = [&](int slot, int t) {
    const float* src = xr + t * 64;
    xp[slot][0] = *(const f32x4*)src;
    xp[slot][1] = *(const f32x4*)(src + 4);
    xp[slot][2] = *(const f32x4*)(src + 32);
    xp[slot][3] = *(const f32x4*)(src + 36);
  };

  stagew(0, 0);
  xload(0, 0);
  xload(1, 1);
  asm volatile("s_waitcnt vmcnt(8)" ::: "memory");   // stagew(0) landed
  __builtin_amdgcn_s_barrier();
  __builtin_amdgcn_sched_barrier(0);

  #pragma unroll
  for (int t = 0; t < 16; t++) {
    const int cur = t & 1;
    if (t < 15) stagew(cur ^ 1, t + 1);
    if (t < 14) xload((t + 2) % 3, t + 2);

    const int slot = t % 3;
    bf16x8 xa[2];
    #pragma unroll
    for (int kc = 0; kc < 2; kc++) {
      union { uint u[4]; bf16x8 v; } h;
      f32x4 c0 = xp[slot][2 * kc], c1 = xp[slot][2 * kc + 1];
      h.u[0] = cvtpk(c0[0], c0[1]); h.u[1] = cvtpk(c0[2], c0[3]);
      h.u[2] = cvtpk(c1[0], c1[1]); h.u[3] = cvtpk(c1[2], c1[3]);
      xa[kc] = h.v;
    }
    const char* wb = (const char*)wl[cur] + lane * 16;
    __builtin_amdgcn_s_setprio(1);
    #pragma unroll
    for (int w = 0; w < 3; w++)
      #pragma unroll
      for (int kc = 0; kc < 2; kc++)
        #pragma unroll
        for (int nt = 0; nt < 4; nt++) {
          bf16x8 wf = *(const bf16x8*)(wb + w * 8192 + kc * 4096 + nt * 1024);
          acc[w][nt] = MFMA(xa[kc], wf, acc[w][nt]);
        }
    __builtin_amdgcn_s_setprio(0);

    if (t < 15) {
      if (t < 14) asm volatile("s_waitcnt vmcnt(4)" ::: "memory");
      else        asm volatile("s_waitcnt vmcnt(0)" ::: "memory");
      __builtin_amdgcn_s_barrier();
      __builtin_amdgcn_sched_barrier(0);
    }
  }

  // epilogue: C-frag col = l15 (n), row = g*4 + r (t offset)  [m89-verified]
  char* kdst = KaF + ((size_t)b * 64 + rt) * 8192;
  char* vdst = VaF + ((size_t)b * 128 + (wrow >> 5)) * 4096;
  #pragma unroll
  for (int nt = 0; nt < 4; nt++) {
    int n = nt * 16 + l15;
    int kc = n >> 5, gp2 = (n >> 3) & 3, j2 = n & 7;
    #pragma unroll
    for (int r = 0; r < 4; r++) {
      int tt = wrow + g * 4 + r;
      Qg[((size_t)b * T_ + tt) * H_ + n] = f2bf(acc[0][nt][r]);
      int key = tt & 63;
      *(ushort*)(kdst + kc * 4096 + (key >> 4) * 1024 +
                 (gp2 * 16 + (key & 15)) * 16 + j2 * 2) = f2bf(acc[1][nt][r]);
      int k5 = tt & 31;
      int gp = ((k5 >> 4) << 1) | ((k5 >> 2) & 1);
      int js = ((k5 >> 3) & 1) * 4 + (k5 & 3);
      *(ushort*)(vdst + nt * 1024 + (gp * 16 + l15) * 16 + js * 2) = f2bf(acc[2][nt][r]);
    }
  }
}

// ---------------------------------------------------------------------------
// Flash attention v6: 32 q-rows/wave (2 subtiles), 128 q/block. Frag-ordered
// K/V tiles staged via global_load_lds into a 3-buffer ring (48KB), 2-deep
// prefetch, counted vmcnt(4) at the barrier (stage stays in flight).
// In-register softmax (swapped QK^T + cvt_pk + permlane32_swap).
// Partials written as bf16.
__global__ __launch_bounds__(256, 2) void attn(const ushort* __restrict__ Qg,
                                               const char* __restrict__ KaF,
                                               const char* __restrict__ VaF,
                                               ushort* __restrict__ Op,
                                               float* __restrict__ Ds,
                                               float* __restrict__ out,
                                               int KT) {
  __shared__ __align__(16) char kv[3][16384];   // ring: [buf][K 8KB | V 8KB]
  const int tid = threadIdx.x;
  const int lane = tid & 63, wid = tid >> 6;
  const int bid = blockIdx.x;
  const int b = bid & 3;                 // XCD spread over batches
  const int qt = (bid >> 2) & 31, s = bid >> 7;
  const int l15 = lane & 15, g = lane >> 4;

  // Q B-frags for 2 q-subtiles: lane l15 = q, k = dim g*8+j
  bf16x8 qa[2][2];
  #pragma unroll
  for (int qs = 0; qs < 2; qs++) {
    const ushort* qp = Qg + ((size_t)b * T_ + qt * 128 + wid * 32 + qs * 16 + l15) * H_ + g * 8;
    qa[qs][0] = *(const bf16x8*)qp;
    qa[qs][1] = *(const bf16x8*)(qp + 32);
  }

  f32x4 oacc[2][4];       // C: O[q=l15][dim = 16*ntd + g*4 + r] per subtile
  #pragma unroll
  for (int qs = 0; qs < 2; qs++)
    #pragma unroll
    for (int nt = 0; nt < 4; nt++) oacc[qs][nt] = (f32x4)0.0f;
  float dsum[2] = {0.f, 0.f};

  const char* kbase = KaF + (size_t)b * 64 * 8192;
  const char* vbase = VaF + (size_t)b * 128 * 4096;
  const int it0 = s * KT;

  auto stage = [&](int buf, int it) {
    char* dst = kv[buf] + tid * 16;
    const char* ks = kbase + (size_t)it * 8192 + tid * 16;
    const char* vs = vbase + (size_t)it * 8192 + tid * 16;
    gload_lds16(ks, dst);
    gload_lds16(ks + 4096, dst + 4096);
    gload_lds16(vs, dst + 8192);
    gload_lds16(vs + 4096, dst + 12288);
  };

  stage(0, it0);
  stage(1, it0 + 1);                     // KT >= 8 always
  asm volatile("s_waitcnt vmcnt(4)" ::: "memory");   // buf0 landed, buf1 in flight
  __builtin_amdgcn_s_barrier();
  __builtin_amdgcn_sched_barrier(0);

  int cur = 0;
  for (int it = 0; it < KT; it++) {
    int pf = cur + 2; if (pf >= 3) pf -= 3;
    if (it + 2 < KT) stage(pf, it0 + it + 2);
    const char* kl = kv[cur];
    const char* vl = kv[cur] + 8192;

    // S^T = K Q^T: each K frag read once, feeds both subtiles
    f32x4 sacc[2][4];
    #pragma unroll
    for (int qs = 0; qs < 2; qs++)
      #pragma unroll
      for (int nt = 0; nt < 4; nt++) sacc[qs][nt] = (f32x4)0.0f;
    __builtin_amdgcn_s_setprio(1);
    #pragma unroll
    for (int nt = 0; nt < 4; nt++)
      #pragma unroll
      for (int kc = 0; kc < 2; kc++) {
        bf16x8 ka = *(const bf16x8*)(kl + kc * 4096 + nt * 1024 + lane * 16);
        sacc[0][nt] = MFMA(ka, qa[0][kc], sacc[0][nt]);
        sacc[1][nt] = MFMA(ka, qa[1][kc], sacc[1][nt]);
      }
    __builtin_amdgcn_s_setprio(0);

    // softmax numerators in-register
    uint t0[2][4], t1[2][4];
    #pragma unroll
    for (int qs = 0; qs < 2; qs++)
      #pragma unroll
      for (int nt = 0; nt < 4; nt++) {
        float p0 = __builtin_amdgcn_exp2f(sacc[qs][nt][0] * 0.18033688011112042f);
        float p1 = __builtin_amdgcn_exp2f(sacc[qs][nt][1] * 0.18033688011112042f);
        float p2 = __builtin_amdgcn_exp2f(sacc[qs][nt][2] * 0.18033688011112042f);
        float p3 = __builtin_amdgcn_exp2f(sacc[qs][nt][3] * 0.18033688011112042f);
        dsum[qs] += (p0 + p1) + (p2 + p3);
        t0[qs][nt] = cvtpk(p0, p1);
        t1[qs][nt] = cvtpk(p2, p3);
      }

    // build P^T B-frags (permlane32_swap) and accumulate O^T += V^T P^T
    #pragma unroll
    for (int kk = 0; kk < 2; kk++) {
      bf16x8 pf2[2];
      #pragma unroll
      for (int qs = 0; qs < 2; qs++) {
        uint x0 = t0[qs][2 * kk], y0 = t0[qs][2 * kk + 1];
        uint x1 = t1[qs][2 * kk], y1 = t1[qs][2 * kk + 1];
        asm volatile("v_permlane32_swap_b32 %0, %1" : "+v"(x0), "+v"(y0));
        asm volatile("v_permlane32_swap_b32 %0, %1" : "+v"(x1), "+v"(y1));
        union { uint u[4]; bf16x8 v; } pfu;
        pfu.u[0] = x0; pfu.u[1] = x1; pfu.u[2] = y0; pfu.u[3] = y1;
        pf2[qs] = pfu.v;
      }
      __builtin_amdgcn_s_setprio(1);
      #pragma unroll
      for (int ntd = 0; ntd < 4; ntd++) {
        bf16x8 va = *(const bf16x8*)(vl + kk * 4096 + ntd * 1024 + lane * 16);
        oacc[0][ntd] = MFMA(va, pf2[0], oacc[0][ntd]);
        oacc[1][ntd] = MFMA(va, pf2[1], oacc[1][ntd]);
      }
      __builtin_amdgcn_s_setprio(0);
    }

    if (it + 1 < KT) {
      // counted drain: stage(it+1) complete, stage(it+2) stays in flight
      if (it + 2 < KT) asm volatile("s_waitcnt vmcnt(4)" ::: "memory");
      else             asm volatile("s_waitcnt vmcnt(0)" ::: "memory");
      __builtin_amdgcn_s_barrier();
      __builtin_amdgcn_sched_barrier(0);
    }
    cur = cur + 1; if (cur >= 3) cur -= 3;
  }

  // epilogue per subtile
  #pragma unroll
  for (int qs = 0; qs < 2; qs++) {
    float d = dsum[qs];
    d += __shfl_xor(d, 16, 64);
    d += __shfl_xor(d, 32, 64);
    const int q = qt * 128 + wid * 32 + qs * 16 + l15;
    if (Op != nullptr) {
      ushort* ob = Op + ((size_t)(s * 4 + b) * T_ + q) * H_;
      #pragma unroll
      for (int nt = 0; nt < 4; nt++) {
        uint2 pk;
        pk.x = cvtpk(oacc[qs][nt][0], oacc[qs][nt][1]);
        pk.y = cvtpk(oacc[qs][nt][2], oacc[qs][nt][3]);
        *(uint2*)(ob + nt * 16 + g * 4) = pk;
      }
      if (g == 0) Ds[(size_t)(s * 4 + b) * T_ + q] = d;
    } else {
      float inv = 1.0f / d;
      float* ob = out + ((size_t)b * T_ + q) * H_;
      #pragma unroll
      for (int nt = 0; nt < 4; nt++)
        #pragma unroll
        for (int r = 0; r < 4; r++) ob[nt * 16 + g * 4 + r] = oacc[qs][nt][r] * inv;
    }
  }
}

// ---------------------------------------------------------------------------
// out[row][h] = sum_s Op[s][row][h] / sum_s Ds[s][row]   (Op is bf16)
__global__ __launch_bounds__(256) void reduce_seg(const ushort* __restrict__ Op,
                                                  const float* __restrict__ Ds,
                                                  float* __restrict__ out, int seg) {
  int i = blockIdx.x * 256 + threadIdx.x;       // over 4*4096*16 groups of 4
  size_t e = (size_t)i * 4;
  int row = (int)(e >> 6);
  f32x4 o = (f32x4)0.0f;
  float d = 0.0f;
  for (int s = 0; s < seg; s++) {
    uint2 pk = *(const uint2*)(Op + (size_t)s * ((size_t)B_ * T_ * H_) + e);
    union { uint u; float f; } c0, c1, c2, c3;
    c0.u = (pk.x & 0xFFFFu) << 16; c1.u = (pk.x >> 16) << 16;
    c2.u = (pk.y & 0xFFFFu) << 16; c3.u = (pk.y >> 16) << 16;
    o[0] += c0.f; o[1] += c1.f; o[2] += c2.f; o[3] += c3.f;
    d += Ds[(size_t)s * ((size_t)B_ * T_) + row];
  }
  *(f32x4*)(out + e) = o * (1.0f / d);
}

// ---------------------------------------------------------------------------
extern "C" void kernel_launch(void* const* d_in, const int* in_sizes, int n_in,
                              void* d_out, int out_size, void* d_ws, size_t ws_size,
                              hipStream_t stream) {
  const float* x  = (const float*)d_in[0];
  const float* Wq = (const float*)d_in[1];
  const float* Wk = (const float*)d_in[2];
  const float* Wv = (const float*)d_in[3];
  float* out = (float*)d_out;

  char* ws = (char*)d_ws;
  size_t off = 0;
  auto take = [&](size_t n) -> void* {
    void* p = ws + off;
    off = (off + n + 255) & ~(size_t)255;
    return p;
  };
  ushort* Qg  = (ushort*)take((size_t)B_ * T_ * H_ * 2);   // 2 MB
  char*   KaF = (char*)take((size_t)B_ * T_ * H_ * 2);     // 2 MB (frag order)
  char*   VaF = (char*)take((size_t)B_ * T_ * H_ * 2);     // 2 MB (frag order)
  ushort* WtF = (ushort*)take((size_t)3 * H_ * C_ * 2);    // 384 KB

  // key-split: largest seg whose bf16 partials fit the workspace
  int seg = 1;
  ushort* Op = nullptr;
  float* Ds = nullptr;
  for (int sg = 4; sg >= 2; sg >>= 1) {
    size_t need = off + (size_t)sg * B_ * T_ * H_ * 2 + 256 + (size_t)sg * B_ * T_ * 4 + 256;
    if (need <= ws_size) {
      seg = sg;
      Op = (ushort*)take((size_t)sg * B_ * T_ * H_ * 2);
      Ds = (float*)take((size_t)sg * B_ * T_ * 4);
      break;
    }
  }
  int KT = 64 / seg;                                       // 64-key tiles/segment

  wt_prep<<<768, 256, 0, stream>>>(Wq, Wk, Wv, WtF);
  qkv_proj<<<B_ * 64, 256, 0, stream>>>(x, WtF, Qg, KaF, VaF);
  attn<<<B_ * (T_ / 128) * seg, 256, 0, stream>>>(Qg, KaF, VaF, Op, Ds, out, KT);
  if (Op) reduce_seg<<<(B_ * T_ * H_ / 4 + 255) / 256, 256, 0, stream>>>(Op, Ds, out, seg);
}

// Round 9
// 53.743 us; speedup vs baseline: 1.1203x; 1.0346x over previous
//
#include <hip/hip_runtime.h>
#include <hip/hip_bf16.h>

#define B_ 4
#define T_ 4096
#define C_ 1024
#define H_ 64

typedef float  f32x4  __attribute__((ext_vector_type(4)));
typedef short  bf16x8 __attribute__((ext_vector_type(8)));
typedef uint   u32x4  __attribute__((ext_vector_type(4)));

static __device__ __forceinline__ ushort f2bf(float f) {
  union { float f; uint u; } v; v.f = f;
  uint u = v.u;
  u += 0x7FFFu + ((u >> 16) & 1u);   // round-to-nearest-even
  return (ushort)(u >> 16);
}

// pack two f32 -> u32 of 2 bf16 (lo = s0, hi = s1), RTNE  [gfx950; no builtin]
static __device__ __forceinline__ uint cvtpk(float s0, float s1) {
  uint r;
  asm("v_cvt_pk_bf16_f32 %0, %1, %2" : "=v"(r) : "v"(s0), "v"(s1));
  return r;
}

static __device__ __forceinline__ void gload_lds16(const void* g, void* l) {
  __builtin_amdgcn_global_load_lds(
      (const __attribute__((address_space(1))) unsigned int*)g,
      (__attribute__((address_space(3))) unsigned int*)l, 16, 0, 0);
}

#define MFMA(a, b, c) __builtin_amdgcn_mfma_f32_16x16x32_bf16(a, b, c, 0, 0, 0)

// ---------------------------------------------------------------------------
// WtF: W in B-frag order: [w][c64 16][kc 2][nt 4][lane 64][j 8]
//   value = W_w[c][n], c = c64*64+kc*32+(lane>>4)*8+j, n = nt*16+(lane&15)
// Wq is pre-scaled by 0.125*log2(e) so attn can use exp2(sacc) directly.
__global__ __launch_bounds__(256) void wt_prep(const float* __restrict__ Wq,
                                               const float* __restrict__ Wk,
                                               const float* __restrict__ Wv,
                                               ushort* __restrict__ WtF) {
  int idx = blockIdx.x * 256 + threadIdx.x;   // 3*65536
  int w = idx >> 16, idx2 = idx & 65535;
  int c = idx2 >> 6, n = idx2 & 63;
  const float* W = (w == 0) ? Wq : (w == 1) ? Wk : Wv;
  float v = W[idx2];
  if (w == 0) v *= 0.18033688011112042f;      // 0.125 * log2(e)
  int c64 = c >> 6, kc = (c >> 5) & 1, g = (c >> 3) & 3, j = c & 7;
  int nt = n >> 4, l15 = n & 15;
  size_t dst = ((size_t)((((w * 16 + c64) * 2 + kc) * 4 + nt) * 64 + g * 16 + l15)) * 8 + j;
  WtF[dst] = f2bf(v);
}

// ---------------------------------------------------------------------------
// QKV projection v4 (unchanged): 4-wave blocks, x direct-to-A-frag 2-deep
// prefetch, W via global_load_lds dbuf, counted-vmcnt raw barriers.
__global__ __launch_bounds__(256) void qkv_proj(const float* __restrict__ x,
                                                const ushort* __restrict__ WtF,
                                                ushort* __restrict__ Qg,
                                                char* __restrict__ KaF,
                                                char* __restrict__ VaF) {
  __shared__ __align__(16) ushort wl[2][12288];   // 2 x 24KB W frags
  const int tid = threadIdx.x;
  const int lane = tid & 63, wid = tid >> 6;
  const int l15 = lane & 15, g = lane >> 4;
  const int b = blockIdx.x >> 6, rt = blockIdx.x & 63;
  const int wrow = rt * 64 + wid * 16;            // wave's 16 rows

  f32x4 acc[3][4];
  #pragma unroll
  for (int w = 0; w < 3; w++)
    #pragma unroll
    for (int nt = 0; nt < 4; nt++) acc[w][nt] = (f32x4)0.0f;

  const float* xr = x + ((size_t)b * T_ + wrow + l15) * C_ + g * 8;

  auto stagew = [&](int buf, int c64) {
    char* dst = (char*)wl[buf] + tid * 16;
    const char* src = (const char*)WtF + (size_t)c64 * 8192 + tid * 16;
    #pragma unroll
    for (int p = 0; p < 6; p++)   // p = w*2 + half(4KB)
      gload_lds16(src + (p >> 1) * 131072 + (p & 1) * 4096, dst + p * 4096);
  };

  f32x4 xp[3][4];                 // 2-deep x prefetch ring (fully unrolled)
  auto xload = [&](int slot, int t) {
    const float* src = xr + t * 64;
    xp[slot][0] = *(const f32x4*)src;
    xp[slot][1] = *(const f32x4*)(src + 4);
    xp[slot][2] = *(const f32x4*)(src + 32);
    xp[slot][3] = *(const f32x4*)(src + 36);
  };

  stagew(0, 0);
  xload(0, 0);
  xload(1, 1);
  asm volatile("s_waitcnt vmcnt(8)" ::: "memory");   // stagew(0) landed
  __builtin_amdgcn_s_barrier();
  __builtin_amdgcn_sched_barrier(0);

  #pragma unroll
  for (int t = 0; t < 16; t++) {
    const int cur = t & 1;
    if (t < 15) stagew(cur ^ 1, t + 1);
    if (t < 14) xload((t + 2) % 3, t + 2);

    const int slot = t % 3;
    bf16x8 xa[2];
    #pragma unroll
    for (int kc = 0; kc < 2; kc++) {
      union { uint u[4]; bf16x8 v; } h;
      f32x4 c0 = xp[slot][2 * kc], c1 = xp[slot][2 * kc + 1];
      h.u[0] = cvtpk(c0[0], c0[1]); h.u[1] = cvtpk(c0[2], c0[3]);
      h.u[2] = cvtpk(c1[0], c1[1]); h.u[3] = cvtpk(c1[2], c1[3]);
      xa[kc] = h.v;
    }
    const char* wb = (const char*)wl[cur] + lane * 16;
    __builtin_amdgcn_s_setprio(1);
    #pragma unroll
    for (int w = 0; w < 3; w++)
      #pragma unroll
      for (int kc = 0; kc < 2; kc++)
        #pragma unroll
        for (int nt = 0; nt < 4; nt++) {
          bf16x8 wf = *(const bf16x8*)(wb + w * 8192 + kc * 4096 + nt * 1024);
          acc[w][nt] = MFMA(xa[kc], wf, acc[w][nt]);
        }
    __builtin_amdgcn_s_setprio(0);

    if (t < 15) {
      if (t < 14) asm volatile("s_waitcnt vmcnt(4)" ::: "memory");
      else        asm volatile("s_waitcnt vmcnt(0)" ::: "memory");
      __builtin_amdgcn_s_barrier();
      __builtin_amdgcn_sched_barrier(0);
    }
  }

  // epilogue: C-frag col = l15 (n), row = g*4 + r (t offset)  [m89-verified]
  char* kdst = KaF + ((size_t)b * 64 + rt) * 8192;
  char* vdst = VaF + ((size_t)b * 128 + (wrow >> 5)) * 4096;
  #pragma unroll
  for (int nt = 0; nt < 4; nt++) {
    int n = nt * 16 + l15;
    int kc = n >> 5, gp2 = (n >> 3) & 3, j2 = n & 7;
    #pragma unroll
    for (int r = 0; r < 4; r++) {
      int tt = wrow + g * 4 + r;
      Qg[((size_t)b * T_ + tt) * H_ + n] = f2bf(acc[0][nt][r]);
      int key = tt & 63;
      *(ushort*)(kdst + kc * 4096 + (key >> 4) * 1024 +
                 (gp2 * 16 + (key & 15)) * 16 + j2 * 2) = f2bf(acc[1][nt][r]);
      int k5 = tt & 31;
      int gp = ((k5 >> 4) << 1) | ((k5 >> 2) & 1);
      int js = ((k5 >> 3) & 1) * 4 + (k5 & 3);
      *(ushort*)(vdst + nt * 1024 + (gp * 16 + l15) * 16 + js * 2) = f2bf(acc[2][nt][r]);
    }
  }
}

// ---------------------------------------------------------------------------
// Flash attention v7: VALU-lean. 32 q-rows/wave (2 subtiles), 128 q/block.
// Frag-ordered K/V tiles in a 3-buffer LDS ring (counted vmcnt). Softmax:
// pre-scaled Q -> p = exp2(sacc); denominator via ones-MFMA (no scalar adds,
// no end shuffles); kk-interleaved exp/cvtpk/permlane (small live set).
__global__ __launch_bounds__(256) void attn(const ushort* __restrict__ Qg,
                                            const char* __restrict__ KaF,
                                            const char* __restrict__ VaF,
                                            ushort* __restrict__ Op,
                                            float* __restrict__ Ds,
                                            float* __restrict__ out,
                                            int KT) {
  __shared__ __align__(16) char kv[3][16384];   // ring: [buf][K 8KB | V 8KB]
  const int tid = threadIdx.x;
  const int lane = tid & 63, wid = tid >> 6;
  const int bid = blockIdx.x;
  const int b = bid & 3;                 // XCD spread over batches
  const int qt = (bid >> 2) & 31, s = bid >> 7;
  const int l15 = lane & 15, g = lane >> 4;

  // Q B-frags for 2 q-subtiles: lane l15 = q, k = dim g*8+j (Q pre-scaled)
  bf16x8 qa[2][2];
  #pragma unroll
  for (int qs = 0; qs < 2; qs++) {
    const ushort* qp = Qg + ((size_t)b * T_ + qt * 128 + wid * 32 + qs * 16 + l15) * H_ + g * 8;
    qa[qs][0] = *(const bf16x8*)qp;
    qa[qs][1] = *(const bf16x8*)(qp + 32);
  }

  // ones A-frag for the denominator MFMA
  union { ushort u[8]; bf16x8 v; } ones_u;
  #pragma unroll
  for (int i = 0; i < 8; i++) ones_u.u[i] = 0x3F80;
  const bf16x8 ones = ones_u.v;

  f32x4 oacc[2][4];       // C: O[q=l15][dim = 16*ntd + g*4 + r] per subtile
  f32x4 dacc[2];          // denominator: C[m][q=l15], all rows equal
  #pragma unroll
  for (int qs = 0; qs < 2; qs++) {
    #pragma unroll
    for (int nt = 0; nt < 4; nt++) oacc[qs][nt] = (f32x4)0.0f;
    dacc[qs] = (f32x4)0.0f;
  }

  const char* kbase = KaF + (size_t)b * 64 * 8192;
  const char* vbase = VaF + (size_t)b * 128 * 4096;
  const int it0 = s * KT;

  auto stage = [&](int buf, int it) {
    char* dst = kv[buf] + tid * 16;
    const char* ks = kbase + (size_t)it * 8192 + tid * 16;
    const char* vs = vbase + (size_t)it * 8192 + tid * 16;
    gload_lds16(ks, dst);
    gload_lds16(ks + 4096, dst + 4096);
    gload_lds16(vs, dst + 8192);
    gload_lds16(vs + 4096, dst + 12288);
  };

  stage(0, it0);
  stage(1, it0 + 1);                     // KT >= 16 always
  asm volatile("s_waitcnt vmcnt(4)" ::: "memory");   // buf0 landed, buf1 in flight
  __builtin_amdgcn_s_barrier();
  __builtin_amdgcn_sched_barrier(0);

  int cur = 0;
  for (int it = 0; it < KT; it++) {
    int pfb = cur + 2; if (pfb >= 3) pfb -= 3;
    if (it + 2 < KT) stage(pfb, it0 + it + 2);
    const char* kl = kv[cur];
    const char* vl = kv[cur] + 8192;

    // S^T = K Q^T: each K frag read once, feeds both subtiles
    f32x4 sacc[2][4];
    #pragma unroll
    for (int qs = 0; qs < 2; qs++)
      #pragma unroll
      for (int nt = 0; nt < 4; nt++) sacc[qs][nt] = (f32x4)0.0f;
    __builtin_amdgcn_s_setprio(1);
    #pragma unroll
    for (int nt = 0; nt < 4; nt++)
      #pragma unroll
      for (int kc = 0; kc < 2; kc++) {
        bf16x8 ka = *(const bf16x8*)(kl + kc * 4096 + nt * 1024 + lane * 16);
        sacc[0][nt] = MFMA(ka, qa[0][kc], sacc[0][nt]);
        sacc[1][nt] = MFMA(ka, qa[1][kc], sacc[1][nt]);
      }
    __builtin_amdgcn_s_setprio(0);

    // per 32-key chunk: exp2 -> pack -> permlane -> PV + ones-MFMA
    #pragma unroll
    for (int kk = 0; kk < 2; kk++) {
      bf16x8 pf2[2];
      #pragma unroll
      for (int qs = 0; qs < 2; qs++) {
        f32x4 sa = sacc[qs][2 * kk], sb = sacc[qs][2 * kk + 1];
        uint x0 = cvtpk(__builtin_amdgcn_exp2f(sa[0]), __builtin_amdgcn_exp2f(sa[1]));
        uint x1 = cvtpk(__builtin_amdgcn_exp2f(sa[2]), __builtin_amdgcn_exp2f(sa[3]));
        uint y0 = cvtpk(__builtin_amdgcn_exp2f(sb[0]), __builtin_amdgcn_exp2f(sb[1]));
        uint y1 = cvtpk(__builtin_amdgcn_exp2f(sb[2]), __builtin_amdgcn_exp2f(sb[3]));
        asm volatile("v_permlane32_swap_b32 %0, %1" : "+v"(x0), "+v"(y0));
        asm volatile("v_permlane32_swap_b32 %0, %1" : "+v"(x1), "+v"(y1));
        union { uint u[4]; bf16x8 v; } pfu;
        pfu.u[0] = x0; pfu.u[1] = x1; pfu.u[2] = y0; pfu.u[3] = y1;
        pf2[qs] = pfu.v;
      }
      __builtin_amdgcn_s_setprio(1);
      #pragma unroll
      for (int ntd = 0; ntd < 4; ntd++) {
        bf16x8 va = *(const bf16x8*)(vl + kk * 4096 + ntd * 1024 + lane * 16);
        oacc[0][ntd] = MFMA(va, pf2[0], oacc[0][ntd]);
        oacc[1][ntd] = MFMA(va, pf2[1], oacc[1][ntd]);
      }
      dacc[0] = MFMA(ones, pf2[0], dacc[0]);
      dacc[1] = MFMA(ones, pf2[1], dacc[1]);
      __builtin_amdgcn_s_setprio(0);
    }

    if (it + 1 < KT) {
      // counted drain: stage(it+1) complete, stage(it+2) stays in flight
      if (it + 2 < KT) asm volatile("s_waitcnt vmcnt(4)" ::: "memory");
      else             asm volatile("s_waitcnt vmcnt(0)" ::: "memory");
      __builtin_amdgcn_s_barrier();
      __builtin_amdgcn_sched_barrier(0);
    }
    cur = cur + 1; if (cur >= 3) cur -= 3;
  }

  // epilogue per subtile: every lane holds its q's denominator in dacc[qs][0]
  #pragma unroll
  for (int qs = 0; qs < 2; qs++) {
    float d = dacc[qs][0];
    const int q = qt * 128 + wid * 32 + qs * 16 + l15;
    if (Op != nullptr) {
      ushort* ob = Op + ((size_t)(s * 4 + b) * T_ + q) * H_;
      #pragma unroll
      for (int nt = 0; nt < 4; nt++) {
        uint2 pk;
        pk.x = cvtpk(oacc[qs][nt][0], oacc[qs][nt][1]);
        pk.y = cvtpk(oacc[qs][nt][2], oacc[qs][nt][3]);
        *(uint2*)(ob + nt * 16 + g * 4) = pk;
      }
      if (g == 0) Ds[(size_t)(s * 4 + b) * T_ + q] = d;
    } else {
      float inv = 1.0f / d;
      float* ob = out + ((size_t)b * T_ + q) * H_;
      #pragma unroll
      for (int nt = 0; nt < 4; nt++)
        #pragma unroll
        for (int r = 0; r < 4; r++) ob[nt * 16 + g * 4 + r] = oacc[qs][nt][r] * inv;
    }
  }
}

// ---------------------------------------------------------------------------
// out[row][h] = sum_s Op[s][row][h] / sum_s Ds[s][row]   (Op is bf16)
__global__ __launch_bounds__(256) void reduce_seg(const ushort* __restrict__ Op,
                                                  const float* __restrict__ Ds,
                                                  float* __restrict__ out, int seg) {
  int i = blockIdx.x * 256 + threadIdx.x;       // over 4*4096*16 groups of 4
  size_t e = (size_t)i * 4;
  int row = (int)(e >> 6);
  f32x4 o = (f32x4)0.0f;
  float d = 0.0f;
  for (int s = 0; s < seg; s++) {
    uint2 pk = *(const uint2*)(Op + (size_t)s * ((size_t)B_ * T_ * H_) + e);
    union { uint u; float f; } c0, c1, c2, c3;
    c0.u = (pk.x & 0xFFFFu) << 16; c1.u = (pk.x >> 16) << 16;
    c2.u = (pk.y & 0xFFFFu) << 16; c3.u = (pk.y >> 16) << 16;
    o[0] += c0.f; o[1] += c1.f; o[2] += c2.f; o[3] += c3.f;
    d += Ds[(size_t)s * ((size_t)B_ * T_) + row];
  }
  *(f32x4*)(out + e) = o * (1.0f / d);
}

// ---------------------------------------------------------------------------
extern "C" void kernel_launch(void* const* d_in, const int* in_sizes, int n_in,
                              void* d_out, int out_size, void* d_ws, size_t ws_size,
                              hipStream_t stream) {
  const float* x  = (const float*)d_in[0];
  const float* Wq = (const float*)d_in[1];
  const float* Wk = (const float*)d_in[2];
  const float* Wv = (const float*)d_in[3];
  float* out = (float*)d_out;

  char* ws = (char*)d_ws;
  size_t off = 0;
  auto take = [&](size_t n) -> void* {
    void* p = ws + off;
    off = (off + n + 255) & ~(size_t)255;
    return p;
  };
  ushort* Qg  = (ushort*)take((size_t)B_ * T_ * H_ * 2);   // 2 MB
  char*   KaF = (char*)take((size_t)B_ * T_ * H_ * 2);     // 2 MB (frag order)
  char*   VaF = (char*)take((size_t)B_ * T_ * H_ * 2);     // 2 MB (frag order)
  ushort* WtF = (ushort*)take((size_t)3 * H_ * C_ * 2);    // 384 KB

  // key-split: largest seg whose bf16 partials fit the workspace
  int seg = 1;
  ushort* Op = nullptr;
  float* Ds = nullptr;
  for (int sg = 4; sg >= 2; sg >>= 1) {
    size_t need = off + (size_t)sg * B_ * T_ * H_ * 2 + 256 + (size_t)sg * B_ * T_ * 4 + 256;
    if (need <= ws_size) {
      seg = sg;
      Op = (ushort*)take((size_t)sg * B_ * T_ * H_ * 2);
      Ds = (float*)take((size_t)sg * B_ * T_ * 4);
      break;
    }
  }
  int KT = 64 / seg;                                       // 64-key tiles/segment

  wt_prep<<<768, 256, 0, stream>>>(Wq, Wk, Wv, WtF);
  qkv_proj<<<B_ * 64, 256, 0, stream>>>(x, WtF, Qg, KaF, VaF);
  attn<<<B_ * (T_ / 128) * seg, 256, 0, stream>>>(Qg, KaF, VaF, Op, Ds, out, KT);
  if (Op) reduce_seg<<<(B_ * T_ * H_ / 4 + 255) / 256, 256, 0, stream>>>(Op, Ds, out, seg);
}